// Round 4
// baseline (527.420 us; speedup 1.0000x reference)
//
#include <hip/hip_runtime.h>

#define BS     4096
#define HIDDEN 2048
#define MAXR   16
#define NSLOT  8
#define NMOD   2
#define OUTW   8192
#define ROWS   8

typedef float f4 __attribute__((ext_vector_type(4)));

// ---------------------------------------------------------------------------
// Expand for ONE module, templated on rank-quads RQ = ceil(R/4) so breg
// indexing is compile-time (runtime-indexed ext_vector arrays -> scratch).
// Per 1024-col tile: cache B slab (RQ*4 x f4) in regs, stream 8 rows:
// uniform LDS inter reads (broadcast), 4*RQ f4 FMAs, one NT float4 store.
// ---------------------------------------------------------------------------
template<int RQ>
__device__ __forceinline__ void expand_mod(
    const float* __restrict__ B, const float* inter_s,
    float* __restrict__ out, int m, int s, int i0, int t)
{
    #pragma unroll 1
    for (int ct = 0; ct < 8; ++ct) {
        const int c0 = ct * 1024 + t * 4;
        const float* Bp = B + (size_t)(m * NSLOT + s) * MAXR * OUTW + c0;
        f4 breg[RQ * 4];
        #pragma unroll
        for (int r = 0; r < RQ * 4; ++r)
            breg[r] = *(const f4*)(Bp + (size_t)r * OUTW);
        #pragma unroll
        for (int j = 0; j < ROWS; ++j) {
            const float* ip = inter_s + j * MAXR;
            f4 acc = (f4)(0.f);
            #pragma unroll
            for (int rq = 0; rq < RQ; ++rq) {
                const f4 w = *(const f4*)(ip + 4 * rq);
                acc += w.x * breg[4*rq+0] + w.y * breg[4*rq+1]
                     + w.z * breg[4*rq+2] + w.w * breg[4*rq+3];
            }
            __builtin_nontemporal_store(acc,
                (f4*)(out + (size_t)(i0 + j) * (NMOD * OUTW) + (size_t)m * OUTW + c0));
        }
    }
}

// ---------------------------------------------------------------------------
// Fused LoRA, module-split: block = (slot s, module m, 8-row chunk).
// Grid 1024 -> 4 blocks/CU (16 waves/CU) for phase staggering.
// hw&7 = s keeps each slot's B panel (+x rows) on one XCD's L2; the two
// module-blocks of the same rows share x via that L2.
// Phase 1 (shrink, own module only): t = (hq=t>>2, q=t&3); per k-step
// 8 f4 x-loads (4 lanes share addr -> one 256B fetch) + 4 f4 A-loads +
// 128 FMAs; unroll 2 pipelines loads under FMAs. Butterfly (lane bits 2,3)
// -> 8KB red LDS -> rank-masked inter in 512B LDS.
// Phase 2: rank-templated expand (above), NT stores.
// ---------------------------------------------------------------------------
__global__ __launch_bounds__(256) void lora_fused(
    const float* __restrict__ x,
    const float* __restrict__ A,
    const float* __restrict__ B,
    const int*   __restrict__ sorted_ids,
    const int*   __restrict__ slot_ranks,
    const int*   __restrict__ slot_offsets,
    float*       __restrict__ out)
{
    __shared__ float red[4 * 4 * ROWS * MAXR];   // 8 KiB (w,g,j,r)
    __shared__ float inter_s[ROWS * MAXR];       // 512 B

    const int t  = threadIdx.x;
    const int hw = blockIdx.x;
    const int s     = hw & 7;          // slot -> XCD
    const int m     = (hw >> 3) & 1;   // module
    const int chunk = hw >> 4;         // 0..63
    const int i0 = slot_offsets[s] + chunk * ROWS;
    const int R  = slot_ranks[s];

    int tok[ROWS];
    #pragma unroll
    for (int j = 0; j < ROWS; ++j) tok[j] = sorted_ids[i0 + j];  // uniform

    const int hq = t >> 2;   // 0..63 : h-quad
    const int q  = t & 3;    // r-quad (r = 4q..4q+3)

    f4 acc[ROWS];
    #pragma unroll
    for (int j = 0; j < ROWS; ++j) acc[j] = (f4)(0.f);

    const float* Ap_base = A + (size_t)(m * NSLOT + s) * (HIDDEN * MAXR);

    #pragma unroll 2
    for (int k = 0; k < 8; ++k) {
        f4 xv[ROWS];
        #pragma unroll
        for (int j = 0; j < ROWS; ++j)
            xv[j] = *(const f4*)(x + (size_t)tok[j] * HIDDEN + 256 * k + 4 * hq);
        const float* Ap = Ap_base + 4096 * k + 64 * hq + 4 * q;
        const f4 a0 = *(const f4*)(Ap);
        const f4 a1 = *(const f4*)(Ap + 16);
        const f4 a2 = *(const f4*)(Ap + 32);
        const f4 a3 = *(const f4*)(Ap + 48);
        #pragma unroll
        for (int j = 0; j < ROWS; ++j) {
            const f4 v = xv[j];
            acc[j] += v.x * a0 + v.y * a1 + v.z * a2 + v.w * a3;
        }
    }

    // butterfly over lane bits 2,3 (low bits of hq)
    #pragma unroll
    for (int j = 0; j < ROWS; ++j) {
        f4 a = acc[j];
        a.x += __shfl_xor(a.x, 4); a.y += __shfl_xor(a.y, 4);
        a.z += __shfl_xor(a.z, 4); a.w += __shfl_xor(a.w, 4);
        a.x += __shfl_xor(a.x, 8); a.y += __shfl_xor(a.y, 8);
        a.z += __shfl_xor(a.z, 8); a.w += __shfl_xor(a.w, 8);
        acc[j] = a;
    }

    if ((t & 12) == 0) {               // lanes 0-3 of each 16-group
        const int w = t >> 6, g = (t >> 4) & 3;
        #pragma unroll
        for (int j = 0; j < ROWS; ++j)
            *(f4*)(red + ((w * 4 + g) * ROWS + j) * MAXR + 4 * q) = acc[j];
    }
    __syncthreads();

    if (t < 128) {   // one (j, r) per thread; sum 16 partials; rank-mask
        const int j = t >> 4, r = t & 15;
        float v = 0.f;
        #pragma unroll
        for (int w = 0; w < 4; ++w)
            #pragma unroll
            for (int g = 0; g < 4; ++g)
                v += red[((w * 4 + g) * ROWS + j) * MAXR + r];
        if (r >= R) v = 0.f;           // rank mask -> expand needs no mask
        inter_s[j * MAXR + r] = v;
    }
    __syncthreads();

    const int rq = (R + 3) >> 2;
    switch (rq) {
        case 1:  expand_mod<1>(B, inter_s, out, m, s, i0, t); break;
        case 2:  expand_mod<2>(B, inter_s, out, m, s, i0, t); break;
        case 3:  expand_mod<3>(B, inter_s, out, m, s, i0, t); break;
        default: expand_mod<4>(B, inter_s, out, m, s, i0, t); break;
    }
}

extern "C" void kernel_launch(void* const* d_in, const int* in_sizes, int n_in,
                              void* d_out, int out_size, void* d_ws, size_t ws_size,
                              hipStream_t stream)
{
    const float* x            = (const float*)d_in[0];
    const float* A            = (const float*)d_in[1];
    const float* B            = (const float*)d_in[2];
    const int*   sorted_ids   = (const int*)d_in[3];
    const int*   slot_ranks   = (const int*)d_in[5];
    const int*   slot_offsets = (const int*)d_in[6];
    float*       out          = (float*)d_out;

    hipLaunchKernelGGL(lora_fused, dim3(BS / ROWS * NMOD), dim3(256), 0, stream,
                       x, A, B, sorted_ids, slot_ranks, slot_offsets, out);
}